// Round 1
// baseline (100.107 us; speedup 1.0000x reference)
//
#include <hip/hip_runtime.h>
#include <cmath>

namespace {
constexpr int HG = 48;
constexpr int NP = HG * HG;        // 2304
constexpr int CH = 16;
constexpr int WIN = 19;            // radius 0.2 * 47 = 9.4 -> offsets -9..9
constexpr int WIN2 = WIN * WIN;    // 361
constexpr float RADIUS = 0.2f;
constexpr float EPS_H = 1e-6f;
constexpr float EPS_T = 1e-8f;
constexpr int KNOTS = 16;
}

__device__ __forceinline__ float lin48(int t) {
    // jnp.linspace(0,1,48): arange*step with endpoint pinned to 1.0
    return (t == HG - 1) ? 1.0f : (float)t * (1.0f / (float)(HG - 1));
}

__device__ __forceinline__ float softplus_f(float v) {
    // jax.nn.softplus = logaddexp(v, 0), stable form
    return fmaxf(v, 0.0f) + log1pf(expf(-fabsf(v)));
}

__global__ __launch_bounds__(256)
void si_blocks_kernel(const float* __restrict__ x,
                      const float* __restrict__ phi_w1,
                      const float* __restrict__ phi_b1,
                      const float* __restrict__ phi_w2,
                      const float* __restrict__ phi_b2,
                      const float* __restrict__ h_w1,
                      const float* __restrict__ h_b1,
                      const float* __restrict__ h_w2,
                      const float* __restrict__ h_b2,
                      const float* __restrict__ S_m,
                      float* __restrict__ out)
{
    const int i = blockIdx.x;
    const int tid = threadIdx.x;
    const int ri = i / HG;
    const int ci = i - ri * HG;
    const float xi = lin48(ri);
    const float yi = lin48(ci);

    __shared__ float4 s_q[32];       // (pre_k, wx_k, wy_k, w2_k)
    __shared__ float  s_Sm[KNOTS];
    __shared__ float  s_h;           // softplus(h_i) + EPS_H
    __shared__ float  s_b2;

    if (tid < 32) {
        const float w0 = phi_w1[tid];
        const float w1 = phi_w1[32 + tid];
        const float pre = xi * w0 + yi * w1 + phi_b1[tid];
        s_q[tid] = make_float4(pre, phi_w1[64 + tid], phi_w1[96 + tid], phi_w2[tid]);
    } else if (tid < 48) {
        s_Sm[tid - 32] = S_m[tid - 32];
    } else if (tid == 64) {
        float hv = h_b2[0];
        #pragma unroll
        for (int k = 0; k < 32; ++k) {
            float t = xi * h_w1[k] + yi * h_w1[32 + k] + h_b1[k];
            t = fmaxf(t, 0.0f);
            hv = fmaf(t, h_w2[k], hv);
        }
        s_h = softplus_f(hv) + EPS_H;
        s_b2 = phi_b2[0];
    }
    __syncthreads();

    const float hval = s_h;
    const float b2 = s_b2;

    float acc[2][CH];
    #pragma unroll
    for (int b = 0; b < 2; ++b)
        #pragma unroll
        for (int c = 0; c < CH; ++c) acc[b][c] = 0.0f;
    float cnt = 0.0f;

    for (int t = tid; t < WIN2; t += 256) {
        const int a = t / WIN;
        const int bb = t - a * WIN;
        const int rj = ri + a - 9;
        const int cj = ci + bb - 9;
        if ((unsigned)rj >= (unsigned)HG || (unsigned)cj >= (unsigned)HG) continue;
        const float xj = lin48(rj);
        const float yj = lin48(cj);
        const float dx = xi - xj;
        const float dy = yi - yj;
        const float dist = sqrtf(dx * dx + dy * dy);
        if (dist > RADIUS) continue;
        cnt += 1.0f;

        // phi MLP: (xi,yi,xj,yj) -> 32 relu -> 1 (query half folded into pre_k)
        float p = b2;
        #pragma unroll
        for (int k = 0; k < 32; ++k) {
            const float4 q = s_q[k];
            float hk = fmaf(xj, q.y, fmaf(yj, q.z, q.x));
            hk = fmaxf(hk, 0.0f);
            p = fmaf(hk, q.w, p);
        }

        // radial spline psi(dist / (h_i + eps))
        float r = dist / hval;
        r = fminf(fmaxf(r, 0.0f), 1.0f);
        int idx = (int)(r * (float)(KNOTS - 1));
        idx = idx > (KNOTS - 2) ? (KNOTS - 2) : idx;
        const float tk  = (float)idx * (1.0f / (float)(KNOTS - 1));
        const float tk1 = (idx == KNOTS - 2) ? 1.0f
                        : (float)(idx + 1) * (1.0f / (float)(KNOTS - 1));
        const float wr = (r - tk) / (tk1 - tk + EPS_T);
        const float psi = (1.0f - wr) * s_Sm[idx] + wr * s_Sm[idx + 1];

        const float w = p * psi;
        const int j = rj * HG + cj;
        const float* xp0 = x + (size_t)j * CH;
        const float* xp1 = xp0 + (size_t)NP * CH;
        #pragma unroll
        for (int c = 0; c < CH; ++c) acc[0][c] = fmaf(w, xp0[c], acc[0][c]);
        #pragma unroll
        for (int c = 0; c < CH; ++c) acc[1][c] = fmaf(w, xp1[c], acc[1][c]);
    }

    // 64-lane butterfly reduction per wave
    #pragma unroll
    for (int off = 32; off > 0; off >>= 1) {
        #pragma unroll
        for (int b = 0; b < 2; ++b)
            #pragma unroll
            for (int c = 0; c < CH; ++c)
                acc[b][c] += __shfl_down(acc[b][c], off, 64);
        cnt += __shfl_down(cnt, off, 64);
    }

    __shared__ float s_red[4][33];
    const int lane = tid & 63;
    const int wv = tid >> 6;
    if (lane == 0) {
        #pragma unroll
        for (int b = 0; b < 2; ++b)
            #pragma unroll
            for (int c = 0; c < CH; ++c)
                s_red[wv][b * CH + c] = acc[b][c];
        s_red[wv][32] = cnt;
    }
    __syncthreads();

    if (tid < 32) {
        const float tot = s_red[0][tid] + s_red[1][tid] + s_red[2][tid] + s_red[3][tid];
        const float cn  = s_red[0][32] + s_red[1][32] + s_red[2][32] + s_red[3][32];
        const float norm = fmaxf(cn, 1.0f);
        const int b = tid >> 4;
        const int c = tid & 15;
        out[(size_t)b * NP * CH + (size_t)i * CH + c] = tot / norm;
    }
}

extern "C" void kernel_launch(void* const* d_in, const int* in_sizes, int n_in,
                              void* d_out, int out_size, void* d_ws, size_t ws_size,
                              hipStream_t stream) {
    const float* x      = (const float*)d_in[0];
    const float* phi_w1 = (const float*)d_in[1];
    const float* phi_b1 = (const float*)d_in[2];
    const float* phi_w2 = (const float*)d_in[3];
    const float* phi_b2 = (const float*)d_in[4];
    const float* h_w1   = (const float*)d_in[5];
    const float* h_b1   = (const float*)d_in[6];
    const float* h_w2   = (const float*)d_in[7];
    const float* h_b2   = (const float*)d_in[8];
    const float* S_m    = (const float*)d_in[9];
    float* out          = (float*)d_out;

    si_blocks_kernel<<<dim3(NP), dim3(256), 0, stream>>>(
        x, phi_w1, phi_b1, phi_w2, phi_b2,
        h_w1, h_b1, h_w2, h_b2, S_m, out);
}

// Round 2
// 84.818 us; speedup vs baseline: 1.1803x; 1.1803x over previous
//
#include <hip/hip_runtime.h>
#include <cmath>

namespace {
constexpr int HG = 48;
constexpr int NP = HG * HG;        // 2304
constexpr int CH = 16;
constexpr int WIN = 19;            // offsets -9..9
constexpr int WIN2 = WIN * WIN;    // 361
constexpr float RADIUS = 0.2f;
constexpr float EPS_H = 1e-6f;
constexpr float EPS_T = 1e-8f;
constexpr int KNOTS = 16;
constexpr int PPB = 4;             // points per block (one per wave)
constexpr int NCAND = 6;           // ceil(361/64)
}

__device__ __forceinline__ float lin48(int t) {
    return (t == HG - 1) ? 1.0f : (float)t * (1.0f / (float)(HG - 1));
}

__device__ __forceinline__ float softplus_f(float v) {
    return fmaxf(v, 0.0f) + log1pf(expf(-fabsf(v)));
}

__global__ __launch_bounds__(256)
void si_blocks_kernel(const float* __restrict__ x,
                      const float* __restrict__ phi_w1,
                      const float* __restrict__ phi_b1,
                      const float* __restrict__ phi_w2,
                      const float* __restrict__ phi_b2,
                      const float* __restrict__ h_w1,
                      const float* __restrict__ h_b1,
                      const float* __restrict__ h_w2,
                      const float* __restrict__ h_b2,
                      const float* __restrict__ S_m,
                      float* __restrict__ out)
{
    const int tid  = threadIdx.x;
    const int lane = tid & 63;
    const int p    = tid >> 6;                 // wave index == point slot
    const int i    = blockIdx.x * PPB + p;     // 576 blocks * 4 = 2304
    const int ri   = i / HG;
    const int ci   = i - ri * HG;
    const float xi = lin48(ri);
    const float yi = lin48(ci);

    __shared__ float4 s_pq[PPB][32];           // (pre_pk, wx_k, wy_k, w2_k)
    __shared__ float2 s_wj[PPB][WIN2];         // (weight, byte offset of j*64)
    __shared__ float  s_Sm[KNOTS];

    // ---- build packed phi weights (threads 0..127), spline knots (128..143)
    if (tid < 128) {
        const int pb = tid >> 5;
        const int k  = tid & 31;
        const int ib = blockIdx.x * PPB + pb;
        const int rb = ib / HG;
        const int cb = ib - rb * HG;
        const float xb = lin48(rb);
        const float yb = lin48(cb);
        const float pre = xb * phi_w1[k] + yb * phi_w1[32 + k] + phi_b1[k];
        s_pq[pb][k] = make_float4(pre, phi_w1[64 + k], phi_w1[96 + k], phi_w2[k]);
    } else if (tid < 128 + KNOTS) {
        s_Sm[tid - 128] = S_m[tid - 128];
    }

    // ---- h_net for this wave's point: 32 lanes cooperate, xor-reduce
    float hval;
    {
        const int k = lane & 31;
        float tk = fmaxf(xi * h_w1[k] + yi * h_w1[32 + k] + h_b1[k], 0.0f) * h_w2[k];
        #pragma unroll
        for (int m = 1; m < 32; m <<= 1) tk += __shfl_xor(tk, m, 64);
        hval = softplus_f(tk + h_b2[0]) + EPS_H;
    }
    const float b2 = phi_b2[0];

    __syncthreads();

    // ---- Phase A: this wave computes weights for its point's 361 candidates
    float xj[NCAND], yj[NCAND], pw[NCAND], accp[NCAND];
    int joff[NCAND];
    float cnt = 0.0f;

    #pragma unroll
    for (int s = 0; s < NCAND; ++s) {
        const int t  = lane + 64 * s;
        const bool in = (t < WIN2);
        const int tt = in ? t : 0;
        const int a  = tt / WIN;
        const int bb = tt - a * WIN;
        const int rj = ri + a - 9;
        const int cj = ci + bb - 9;
        const bool valid = in && ((unsigned)rj < (unsigned)HG) && ((unsigned)cj < (unsigned)HG);
        const int rjc = min(max(rj, 0), HG - 1);
        const int cjc = min(max(cj, 0), HG - 1);
        const float xjv = lin48(rjc);
        const float yjv = lin48(cjc);
        const float dx = xi - xjv;
        const float dy = yi - yjv;
        const float dist = sqrtf(dx * dx + dy * dy);
        const float m = (valid && dist <= RADIUS) ? 1.0f : 0.0f;
        cnt += m;

        float r = fminf(dist / hval, 1.0f);
        int idx = (int)(r * (float)(KNOTS - 1));
        idx = idx > (KNOTS - 2) ? (KNOTS - 2) : idx;
        const float tk  = (float)idx * (1.0f / (float)(KNOTS - 1));
        const float tk1 = (idx == KNOTS - 2) ? 1.0f
                        : (float)(idx + 1) * (1.0f / (float)(KNOTS - 1));
        const float wr  = (r - tk) / (tk1 - tk + EPS_T);
        const float psi = (1.0f - wr) * s_Sm[idx] + wr * s_Sm[idx + 1];

        pw[s]   = psi * m;
        xj[s]   = xjv;
        yj[s]   = yjv;
        accp[s] = b2;
        joff[s] = (rjc * HG + cjc) * 64;   // byte offset into x row (16 fp32)
    }

    // valid-neighbor count -> 1/norm (all lanes get total via xor butterfly)
    #pragma unroll
    for (int m = 1; m < 64; m <<= 1) cnt += __shfl_xor(cnt, m, 64);
    const float rnorm = 1.0f / fmaxf(cnt, 1.0f);

    // phi MLP, loop-swapped: one broadcast LDS read serves all 6 candidates
    #pragma unroll
    for (int k = 0; k < 32; ++k) {
        const float4 q = s_pq[p][k];
        #pragma unroll
        for (int s = 0; s < NCAND; ++s) {
            float hk = fmaf(xj[s], q.y, fmaf(yj[s], q.z, q.x));
            hk = fmaxf(hk, 0.0f);
            accp[s] = fmaf(hk, q.w, accp[s]);
        }
    }

    #pragma unroll
    for (int s = 0; s < NCAND; ++s) {
        const int t = lane + 64 * s;
        if (t < WIN2) {
            const float w = accp[s] * pw[s] * rnorm;
            s_wj[p][t] = make_float2(w, __int_as_float(joff[s]));
        }
    }

    __syncthreads();

    // ---- Phase B: 64 lanes per point = 8 reps x (2 batches x 4-chan groups)
    const int rep = (lane >> 3) & 7;
    const int pc  = lane & 7;
    const int b   = pc >> 2;
    const int c4  = pc & 3;
    const char* xbase = (const char*)x + (size_t)(b * NP * CH + c4 * 4) * 4;

    float4 acc = make_float4(0.0f, 0.0f, 0.0f, 0.0f);
    #pragma unroll 4
    for (int t = rep; t < WIN2; t += 8) {
        const float2 wj = s_wj[p][t];
        const float4 xv = *(const float4*)(xbase + __float_as_int(wj.y));
        acc.x = fmaf(wj.x, xv.x, acc.x);
        acc.y = fmaf(wj.x, xv.y, acc.y);
        acc.z = fmaf(wj.x, xv.z, acc.z);
        acc.w = fmaf(wj.x, xv.w, acc.w);
    }

    #pragma unroll
    for (int off = 8; off < 64; off <<= 1) {
        acc.x += __shfl_down(acc.x, off, 64);
        acc.y += __shfl_down(acc.y, off, 64);
        acc.z += __shfl_down(acc.z, off, 64);
        acc.w += __shfl_down(acc.w, off, 64);
    }

    if (rep == 0) {
        float4* op = (float4*)(out + (size_t)(b * NP + i) * CH + c4 * 4);
        *op = acc;
    }
}

extern "C" void kernel_launch(void* const* d_in, const int* in_sizes, int n_in,
                              void* d_out, int out_size, void* d_ws, size_t ws_size,
                              hipStream_t stream) {
    const float* x      = (const float*)d_in[0];
    const float* phi_w1 = (const float*)d_in[1];
    const float* phi_b1 = (const float*)d_in[2];
    const float* phi_w2 = (const float*)d_in[3];
    const float* phi_b2 = (const float*)d_in[4];
    const float* h_w1   = (const float*)d_in[5];
    const float* h_b1   = (const float*)d_in[6];
    const float* h_w2   = (const float*)d_in[7];
    const float* h_b2   = (const float*)d_in[8];
    const float* S_m    = (const float*)d_in[9];
    float* out          = (float*)d_out;

    si_blocks_kernel<<<dim3(NP / PPB), dim3(256), 0, stream>>>(
        x, phi_w1, phi_b1, phi_w2, phi_b2,
        h_w1, h_b1, h_w2, h_b2, S_m, out);
}